// Round 8
// baseline (739.360 us; speedup 1.0000x reference)
//
#include <hip/hip_runtime.h>
#include <hip/hip_bf16.h>

#define BB 64
#define NN 256
#define DD 512
#define EE 10

typedef __bf16 bf16x8 __attribute__((ext_vector_type(8)));
typedef unsigned short ushort8v __attribute__((ext_vector_type(8)));
typedef unsigned int uint4v __attribute__((ext_vector_type(4)));
typedef unsigned int uint2v __attribute__((ext_vector_type(2)));
typedef float floatx4 __attribute__((ext_vector_type(4)));
typedef float floatx16 __attribute__((ext_vector_type(16)));

__device__ __forceinline__ unsigned short f2b(float f) {
    union { float f; unsigned u; } x; x.f = f;
    unsigned r = x.u + 0x7FFFu + ((x.u >> 16) & 1u);
    return (unsigned short)(r >> 16);
}
__device__ __forceinline__ float b2f(unsigned short u) {
    union { unsigned u; float f; } x; x.u = ((unsigned)u) << 16;
    return x.f;
}
// pack two rounded bf16 (hi=a, lo=b) from f32 bit patterns via byte-perm
__device__ __forceinline__ unsigned pack_bf16(float a, float b) {
    union { float f; unsigned u; } xa, xb2; xa.f = a; xb2.f = b;
    return __builtin_amdgcn_perm(xa.u + 0x8000u, xb2.u + 0x8000u, 0x07060302u);
}
// build bf16x8 {0,1.0} fragment from two nibble-expanded byte masks
// (n0,n1 hold 0x01/0x00 bytes for bits 0..3 / 4..7). 8 VALU total.
__device__ __forceinline__ bf16x8 frag_from_nibs(unsigned n0, unsigned n1) {
    unsigned r80a = n0 << 7, r80b = n1 << 7;
    unsigned r3fa = n0 * 63u, r3fb = n1 * 63u;   // 63 = inline const
    uint4v av;
    av[0] = __builtin_amdgcn_perm(r3fa, r80a, 0x05010400u);  // elems 0,1
    av[1] = __builtin_amdgcn_perm(r3fa, r80a, 0x07030602u);  // elems 2,3
    av[2] = __builtin_amdgcn_perm(r3fb, r80b, 0x05010400u);  // elems 4,5
    av[3] = __builtin_amdgcn_perm(r3fb, r80b, 0x07030602u);  // elems 6,7
    return __builtin_bit_cast(bf16x8, av);
}

// ---------------- K0a: W_edge/W_self -> Wf in 32x32x16 MFMA-B fragment order.
__global__ void k_wconv(const float* __restrict__ W_edge,
                        const float* __restrict__ W_self,
                        unsigned short* __restrict__ Wf) {
    int t = blockIdx.x * 256 + threadIdx.x;   // grid 1408 -> 360448 exact
    int lane  = t & 63;
    int kstep = (t >> 6) & 31;
    int cfg   = (t >> 11) & 15;
    int e     = t >> 15;                      // 0..10
    int dout = cfg * 32 + (lane & 31);
    int k    = kstep * 16 + (lane >> 5) * 8;
    const float* src = (e < EE) ? (W_edge + ((size_t)e * DD + dout) * DD + k)
                                : (W_self + (size_t)dout * DD + k);
    ushort8v o;
    #pragma unroll
    for (int j = 0; j < 8; j++) o[j] = f2b(src[j]);
    *(ushort8v*)(Wf + (size_t)t * 8) = o;
}

// ---------------- K0b: pack graph bits + recip(neigh). One block per (b,n).
__global__ void k_graph(const int* __restrict__ adj, const int* __restrict__ mask,
                        unsigned* __restrict__ packed, float* __restrict__ recip) {
    int b = blockIdx.x >> 8;
    int n = blockIdx.x & 255;
    int lane = threadIdx.x & 63;
    int wv   = threadIdx.x >> 6;   // 0..3
    int m = wv * 64 + lane;
    int ok = (mask[b * NN + n] != 0) & (mask[b * NN + m] != 0) & (m != n);
    __shared__ int cnt_s[4];
    int total = 0;
    #pragma unroll
    for (int e = 0; e < EE; e++) {
        int a = adj[(((size_t)e * BB + b) * NN + n) * NN + m];
        int bit = ok & (a != 0);
        unsigned long long bal = __ballot(bit);
        if (lane == 0) {
            unsigned* dst = packed + (((size_t)e * BB + b) * NN + n) * 8 + wv * 2;
            dst[0] = (unsigned)bal;
            dst[1] = (unsigned)(bal >> 32);
        }
        total += bit;
    }
    for (int off = 32; off; off >>= 1) total += __shfl_down(total, off);
    if (lane == 0) cnt_s[wv] = total;
    __syncthreads();
    if (threadIdx.x == 0) {
        int c = cnt_s[0] + cnt_s[1] + cnt_s[2] + cnt_s[3];
        recip[b * NN + n] = 1.0f / (float)(c < 1 ? 1 : c);
    }
}

// ---------------- K1 fused: gate + bf16 copy + frag-order wTf build.
// Grid 1024 = (b, ms): block handles 16 rows (n = ms*16..+16) x 512 d.
template<int TI>
__global__ __launch_bounds__(256)
void k_gt(const float* __restrict__ xf, const unsigned short* __restrict__ xbin,
          const float* __restrict__ W_nw, const float* __restrict__ b_nw,
          float* __restrict__ w_out, unsigned short* __restrict__ wTf,
          unsigned short* __restrict__ xb0) {
    int bid = blockIdx.x;
    int b  = bid >> 4;
    int ms = bid & 15;
    __shared__ float part[16][17];
    __shared__ float wsig[16];
    int t = threadIdx.x;
    int row = t >> 4;          // 0..15 local n
    int seg = t & 15;          // 32-d segment
    size_t g = ((size_t)(b * NN + ms * 16 + row)) * DD + seg * 32;
    float s = 0.f;
    if (TI == 0) {
        const floatx4* xp = (const floatx4*)(xf + g);
        const floatx4* wp = (const floatx4*)(W_nw + seg * 32);
        #pragma unroll
        for (int k = 0; k < 4; k++) {
            floatx4 a = xp[2 * k], c4 = xp[2 * k + 1];
            floatx4 wa = wp[2 * k], wc = wp[2 * k + 1];
            ushort8v u;
            #pragma unroll
            for (int j = 0; j < 4; j++) {
                s += a[j] * wa[j] + c4[j] * wc[j];
                u[j] = f2b(a[j]); u[4 + j] = f2b(c4[j]);
            }
            *(ushort8v*)(xb0 + g + k * 8) = u;
        }
    } else {
        const ushort8v* xp = (const ushort8v*)(xbin + g);
        const float* wp = W_nw + seg * 32;
        #pragma unroll
        for (int k = 0; k < 4; k++) {
            ushort8v u = xp[k];
            #pragma unroll
            for (int j = 0; j < 8; j++) s += b2f(u[j]) * wp[k * 8 + j];
        }
    }
    part[row][seg] = s;
    __syncthreads();
    if (t < 16) {
        float tot = 0.f;
        #pragma unroll
        for (int i = 0; i < 16; i++) tot += part[t][i];
        float v = 1.f / (1.f + __expf(-(tot + b_nw[0])));
        wsig[t] = v;
        w_out[(b * 2 + TI) * NN + ms * 16 + t] = v;
    }
    __syncthreads();
    // phase 2: write wTf frag-order (elem j = x[m=ms*16+hi*8+j][dd*32+l31] * w[m])
    #pragma unroll
    for (int c = 0; c < 4; c++) {
        int slot = t + 256 * c;          // 0..1023
        int dd_  = slot >> 6;            // 0..15
        int lane = slot & 63;
        int l31 = lane & 31, hi = lane >> 5;
        size_t xrow = ((size_t)(b * NN + ms * 16 + hi * 8)) * DD + dd_ * 32 + l31;
        ushort8v o;
        #pragma unroll
        for (int j = 0; j < 8; j++) {
            float xv = (TI == 0) ? xf[xrow + (size_t)j * DD] : b2f(xbin[xrow + (size_t)j * DD]);
            o[j] = f2b(xv * wsig[hi * 8 + j]);
        }
        *(ushort8v*)(wTf + ((((size_t)b * 16 + ms) * 16 + dd_) * 64 + lane) * 8) = o;
    }
}

// ---------------- K2 v9: NO LDS staging. Since wTf is already in MFMA frag
// order, stage-1 reads its A-fragments DIRECT from global (1KB coalesced,
// L2-resident, shared by the 4 nq-siblings on the same XCD) -- just like
// stage-2 already reads Wf direct. Eliminates sWT (64KB), all global_load_lds,
// both vmcnt(0) drains, and one barrier. Per step: 16+16 MFMA/wave, ONE
// lgkmcnt(0)+barrier (sTf handoff). sTf double-buffered: a fast wave cannot
// rewrite sTf[cur] (step s+2) before passing barrier(s+1), which the slow
// reader of step s reached only after finishing its reads -> race-free.
// LDS = 32KB; tile 64n x 256dout; grid 512 = 2 blocks/CU. VALU diet,
// deferred recip, math/layout identical to v8 (verified).
template<int TI>
__global__ __launch_bounds__(512, 4)
void k2_heavy(const unsigned short* __restrict__ wTf,   // [b][ms16][dd16][lane][8] frag order
              const unsigned short* __restrict__ xb,    // [B][N][D] bf16 (self A)
              const unsigned short* __restrict__ Wf,    // 32x32 frag order [11][cf16][ks32][lane][8]
              const unsigned* __restrict__ packed,      // [E][B][N][8]
              const float* __restrict__ recip,          // [B][N]
              const float* __restrict__ b_self,         // [D]
              unsigned short* __restrict__ out_bf16,    // t=0
              float* __restrict__ out_f32) {            // t=1
    __shared__ __attribute__((aligned(16))) unsigned short sTf[2][16 * 512]; // 2 x 16 KB

    int bid = blockIdx.x;
    int ct = bid & 1;                  // 256-dout half
    int b  = (bid >> 1) & 63;
    int nq = bid >> 7;                 // 64-row n quarter
    int w = threadIdx.x >> 6, lane = threadIdx.x & 63;
    int l31 = lane & 31, hi = lane >> 5;

    // stage-1 role (all waves): s1_d = 32d chunk of 128, s1_nb = 32n half
    int s1_d = w >> 1, s1_nb = w & 1;
    int gn1 = nq * 64 + s1_nb * 32 + l31;         // global n (stage-1 C col)
    // stage-2 role (all waves): w = 32-dout column within ct-half

    floatx16 acc2[2];                             // [nb 32n-half]
    #pragma unroll
    for (int i = 0; i < 2; i++)
        #pragma unroll
        for (int q = 0; q < 16; q++) acc2[i][q] = 0.f;

    const unsigned short* WfL = Wf + lane * 8;
    const unsigned short* xbL = xb + ((size_t)(b * NN + nq * 64 + l31)) * DD + hi * 8;
    // stage-1 A-frag base: frag (mk, dc2) at wTfA + (mk*16 + dc2*4)*512
    const unsigned short* wTfA = wTf + ((size_t)b * 256 + s1_d) * 512 + lane * 8;

    unsigned bq[32];  // per-e nibble-expanded graph masks (0x01-bytes)

    #pragma unroll 1
    for (int s = 0; s < 40; s++) {
        int e = s >> 2, dc2 = s & 3, cur = s & 1;
        if ((s & 3) == 0) {
            // refresh bq once per e (bits -> 0x01-bytes via nibble-spread mul)
            const uint4v* pp = (const uint4v*)(packed +
                (((size_t)e * BB + b) * NN + gn1) * 8);
            uint4v pa = pp[0], pbv = pp[1];
            unsigned pwv[8] = {pa[0], pa[1], pa[2], pa[3], pbv[0], pbv[1], pbv[2], pbv[3]};
            #pragma unroll
            for (int ks = 0; ks < 8; ks++) {
                unsigned byA = (pwv[ks] >> (hi * 8)) & 0xFFu;
                unsigned byB = (pwv[ks] >> ((2 + hi) * 8)) & 0xFFu;
                bq[ks * 4 + 0] = ((byA & 0xFu) * 0x00204081u) & 0x01010101u;
                bq[ks * 4 + 1] = (((byA >> 4) & 0xFu) * 0x00204081u) & 0x01010101u;
                bq[ks * 4 + 2] = ((byB & 0xFu) * 0x00204081u) & 0x01010101u;
                bq[ks * 4 + 3] = (((byB >> 4) & 0xFu) * 0x01010101u & 0x01010101u);
            }
            // NOTE: line above must match the others; fixed below
            #pragma unroll
            for (int ks = 0; ks < 8; ks++) {
                unsigned byB = (pwv[ks] >> ((2 + hi) * 8)) & 0xFFu;
                bq[ks * 4 + 3] = (((byB >> 4) & 0xFu) * 0x00204081u) & 0x01010101u;
            }
        }
        // ---- stage 1 (all waves): 32d x 32n frag of S^T, K=256, A from global --
        {
            floatx16 acc3;
            #pragma unroll
            for (int q = 0; q < 16; q++) acc3[q] = 0.f;
            #pragma unroll
            for (int mk = 0; mk < 16; mk++) {
                bf16x8 afr = __builtin_bit_cast(bf16x8,
                    *(const ushort8v*)&wTfA[(size_t)(mk * 16 + dc2 * 4) * 512]);
                bf16x8 bg = frag_from_nibs(bq[(mk >> 1) * 4 + (mk & 1) * 2],
                                           bq[(mk >> 1) * 4 + (mk & 1) * 2 + 1]);
                acc3 = __builtin_amdgcn_mfma_f32_32x32x16_bf16(afr, bg, acc3, 0, 0, 0);
            }
            // pack (recip deferred), write frag-order sTf[cur]
            #pragma unroll
            for (int g = 0; g < 4; g++) {
                uint2v pk;
                pk[0] = pack_bf16(acc3[g * 4 + 1], acc3[g * 4 + 0]);
                pk[1] = pack_bf16(acc3[g * 4 + 3], acc3[g * 4 + 2]);
                int kk_w = s1_d * 2 + (g >> 1);           // 16-d chunk of 128
                int slot = (kk_w * 2 + s1_nb) * 64 + (g & 1) * 32 + l31;
                *(uint2v*)&sTf[cur][slot * 8 + 4 * hi] = pk;
            }
        }
        // ---- the ONE barrier: sTf[cur] writes visible ----
        asm volatile("s_waitcnt lgkmcnt(0)" ::: "memory");
        __builtin_amdgcn_s_barrier();
        // ---- stage 2 (all waves): acc2 += S(64n x 128d) @ Wf col (32 dout) --
        #pragma unroll
        for (int kk = 0; kk < 8; kk++) {
            bf16x8 bfr = __builtin_bit_cast(bf16x8, *(const ushort8v*)
                &WfL[(size_t)(((e * 16 + ct * 8 + w) * 32 + dc2 * 8 + kk)) * 512]);
            bf16x8 afr0 = __builtin_bit_cast(bf16x8,
                *(const ushort8v*)&sTf[cur][((kk * 2 + 0) * 64 + lane) * 8]);
            bf16x8 afr1 = __builtin_bit_cast(bf16x8,
                *(const ushort8v*)&sTf[cur][((kk * 2 + 1) * 64 + lane) * 8]);
            acc2[0] = __builtin_amdgcn_mfma_f32_32x32x16_bf16(afr0, bfr, acc2[0], 0, 0, 0);
            acc2[1] = __builtin_amdgcn_mfma_f32_32x32x16_bf16(afr1, bfr, acc2[1], 0, 0, 0);
        }
    }
    // ---- transition: apply deferred 1/neigh to the edge aggregate ----
    #pragma unroll
    for (int nb = 0; nb < 2; nb++) {
        #pragma unroll
        for (int rg = 0; rg < 16; rg++) {
            int row = nq * 64 + nb * 32 + (rg & 3) + 8 * (rg >> 2) + 4 * hi;
            acc2[nb][rg] *= recip[b * NN + row];
        }
    }
    // ---- self path: A direct from xb, barrier-free tail (unscaled) ----
    #pragma unroll 1
    for (int dc2 = 0; dc2 < 4; dc2++) {
        #pragma unroll
        for (int kk = 0; kk < 8; kk++) {
            bf16x8 bfr = __builtin_bit_cast(bf16x8, *(const ushort8v*)
                &WfL[(size_t)(((EE * 16 + ct * 8 + w) * 32 + dc2 * 8 + kk)) * 512]);
            bf16x8 afr0 = __builtin_bit_cast(bf16x8, *(const ushort8v*)
                &xbL[(size_t)0 * 32 * DD + (dc2 * 8 + kk) * 16]);
            bf16x8 afr1 = __builtin_bit_cast(bf16x8, *(const ushort8v*)
                &xbL[(size_t)1 * 32 * DD + (dc2 * 8 + kk) * 16]);
            acc2[0] = __builtin_amdgcn_mfma_f32_32x32x16_bf16(afr0, bfr, acc2[0], 0, 0, 0);
            acc2[1] = __builtin_amdgcn_mfma_f32_32x32x16_bf16(afr1, bfr, acc2[1], 0, 0, 0);
        }
    }
    // ---- epilogue: +b_self, relu, store (C rows=n, cols=dout) ----
    {
        int col = ct * 256 + w * 32 + l31;
        float bs = b_self[col];
        #pragma unroll
        for (int nb = 0; nb < 2; nb++) {
            #pragma unroll
            for (int rg = 0; rg < 16; rg++) {
                int row = nq * 64 + nb * 32 + (rg & 3) + 8 * (rg >> 2) + 4 * hi;
                float v = acc2[nb][rg] + bs;
                v = v > 0.f ? v : 0.f;
                size_t gi = ((size_t)b * NN + row) * DD + col;
                if (TI == 0) out_bf16[gi] = f2b(v);
                else         out_f32[gi] = v;
            }
        }
    }
}

extern "C" void kernel_launch(void* const* d_in, const int* in_sizes, int n_in,
                              void* d_out, int out_size, void* d_ws, size_t ws_size,
                              hipStream_t stream) {
    const float* node   = (const float*)d_in[0];
    const float* W_nw   = (const float*)d_in[1];
    const float* b_nw   = (const float*)d_in[2];
    const float* W_self = (const float*)d_in[3];
    const float* b_self = (const float*)d_in[4];
    const float* W_edge = (const float*)d_in[5];
    const int*   mask   = (const int*)d_in[6];
    const int*   adj    = (const int*)d_in[7];
    float* out = (float*)d_out;
    float* out_w = out + (size_t)BB * NN * DD;   // all_weight region [B][2][N]

    char* ws = (char*)d_ws;
    size_t off = 0;
    unsigned short* Wf    = (unsigned short*)(ws + off); off += (size_t)11 * DD * DD * 2;      // 5.77 MB
    unsigned short* wTf   = (unsigned short*)(ws + off); off += (size_t)BB * DD * NN * 2;      // 16.78 MB
    unsigned short* xb0   = (unsigned short*)(ws + off); off += (size_t)BB * NN * DD * 2;      // 16.78 MB
    unsigned short* xb1   = (unsigned short*)(ws + off); off += (size_t)BB * NN * DD * 2;      // 16.78 MB
    unsigned*       packed= (unsigned*)(ws + off);       off += (size_t)EE * BB * NN * 8 * 4;  // 5.24 MB
    float*          recip = (float*)(ws + off);          off += (size_t)BB * NN * 4;

    k_wconv<<<dim3(1408), dim3(256), 0, stream>>>(W_edge, W_self, Wf);
    k_graph<<<dim3(16384), dim3(256), 0, stream>>>(adj, mask, packed, recip);

    // iteration 0
    k_gt<0><<<dim3(1024), dim3(256), 0, stream>>>(node, nullptr, W_nw, b_nw, out_w, wTf, xb0);
    k2_heavy<0><<<dim3(512), dim3(512), 0, stream>>>(wTf, xb0, Wf, packed, recip, b_self, xb1, nullptr);

    // iteration 1
    k_gt<1><<<dim3(1024), dim3(256), 0, stream>>>(nullptr, xb1, W_nw, b_nw, out_w, wTf, nullptr);
    k2_heavy<1><<<dim3(512), dim3(512), 0, stream>>>(wTf, xb1, Wf, packed, recip, b_self, nullptr, out);
}